// Round 1
// baseline (192.441 us; speedup 1.0000x reference)
//
#include <hip/hip_runtime.h>

#define XDIM 300
#define YDIM 300
#define ZDIM 300
#define CCH 16
#define NPTS 1048576

// ---------------------------------------------------------------------------
// Transpose (C, HW) -> (HW, C) for three tensors at once (blockIdx.y selects).
// LDS-tiled: coalesced reads along pixels, coalesced writes along channels.
// ---------------------------------------------------------------------------
__global__ __launch_bounds__(256) void transpose3(
    const float* __restrict__ a, const float* __restrict__ b, const float* __restrict__ c,
    float* __restrict__ ta, float* __restrict__ tb, float* __restrict__ tc, int HW)
{
    const float* in  = (blockIdx.y == 0) ? a  : (blockIdx.y == 1) ? b  : c;
    float*       out = (blockIdx.y == 0) ? ta : (blockIdx.y == 1) ? tb : tc;

    __shared__ float tile[64][CCH + 1];
    int pix0 = blockIdx.x * 64;
    int t = threadIdx.x;

    // read phase: 64 pixels x 16 channels, coalesced along pixels
    int p  = t & 63;
    int cg = t >> 6;   // 0..3
#pragma unroll
    for (int k = 0; k < 4; ++k) {
        int ch  = cg * 4 + k;
        int pix = pix0 + p;
        tile[p][ch] = (pix < HW) ? in[(size_t)ch * HW + pix] : 0.f;
    }
    __syncthreads();

    // write phase: out[pix*16 + ch], coalesced
    int ch = t & 15;
    int pr = t >> 4;   // 0..15
#pragma unroll
    for (int k = 0; k < 4; ++k) {
        int p2  = pr + k * 16;
        int pix = pix0 + p2;
        if (pix < HW) out[(size_t)pix * CCH + ch] = tile[p2][ch];
    }
}

// ---------------------------------------------------------------------------
// Sampling helpers. TRANS=true: tex layout (H*W, C), fetch float4 per corner.
// TRANS=false: original (C, H, W) layout, 4 scalar fetches per corner.
// q = channel quad index (0..3), covers channels q*4 .. q*4+3.
// ---------------------------------------------------------------------------
__device__ __forceinline__ float4 fma4(float4 acc, float4 v, float w) {
    acc.x += v.x * w; acc.y += v.y * w; acc.z += v.z * w; acc.w += v.w * w;
    return acc;
}
__device__ __forceinline__ float4 mul4(float4 a, float4 b) {
    return make_float4(a.x * b.x, a.y * b.y, a.z * b.z, a.w * b.w);
}

template <bool TRANS>
__device__ __forceinline__ float4 bilinear4(const float* __restrict__ tex,
                                            float gx, float gy, int W, int H, int q)
{
    float ix = (gx + 1.f) * 0.5f * (float)(W - 1);
    float iy = (gy + 1.f) * 0.5f * (float)(H - 1);
    float ix0f = floorf(ix), iy0f = floorf(iy);
    float wx = ix - ix0f, wy = iy - iy0f;
    int ix0 = min(max((int)ix0f, 0), W - 1);
    int ix1 = min(ix0 + 1, W - 1);
    int iy0 = min(max((int)iy0f, 0), H - 1);
    int iy1 = min(iy0 + 1, H - 1);
    float w00 = (1.f - wx) * (1.f - wy);
    float w01 = wx * (1.f - wy);
    float w10 = (1.f - wx) * wy;
    float w11 = wx * wy;

    float4 r = make_float4(0.f, 0.f, 0.f, 0.f);
    if (TRANS) {
        const float4* t4 = (const float4*)tex;
        float4 v00 = t4[(size_t)(iy0 * W + ix0) * (CCH / 4) + q];
        float4 v01 = t4[(size_t)(iy0 * W + ix1) * (CCH / 4) + q];
        float4 v10 = t4[(size_t)(iy1 * W + ix0) * (CCH / 4) + q];
        float4 v11 = t4[(size_t)(iy1 * W + ix1) * (CCH / 4) + q];
        r = fma4(r, v00, w00);
        r = fma4(r, v01, w01);
        r = fma4(r, v10, w10);
        r = fma4(r, v11, w11);
    } else {
        size_t hw = (size_t)H * W;
        int b00 = iy0 * W + ix0, b01 = iy0 * W + ix1;
        int b10 = iy1 * W + ix0, b11 = iy1 * W + ix1;
        float rr[4];
#pragma unroll
        for (int j = 0; j < 4; ++j) {
            size_t cb = (size_t)(q * 4 + j) * hw;
            rr[j] = tex[cb + b00] * w00 + tex[cb + b01] * w01 +
                    tex[cb + b10] * w10 + tex[cb + b11] * w11;
        }
        r = make_float4(rr[0], rr[1], rr[2], rr[3]);
    }
    return r;
}

template <bool TRANS>
__device__ __forceinline__ float4 linear4(const float* __restrict__ tex,
                                          float g, int H, int q)
{
    // W == 1 in the reference => ix = 0, wx = 0; only the y-lerp survives.
    float iy = (g + 1.f) * 0.5f * (float)(H - 1);
    float iy0f = floorf(iy);
    float wy = iy - iy0f;
    int iy0 = min(max((int)iy0f, 0), H - 1);
    int iy1 = min(iy0 + 1, H - 1);

    float4 r = make_float4(0.f, 0.f, 0.f, 0.f);
    if (TRANS) {
        const float4* t4 = (const float4*)tex;
        float4 v0 = t4[(size_t)iy0 * (CCH / 4) + q];
        float4 v1 = t4[(size_t)iy1 * (CCH / 4) + q];
        r = fma4(r, v0, 1.f - wy);
        r = fma4(r, v1, wy);
    } else {
        float rr[4];
#pragma unroll
        for (int j = 0; j < 4; ++j) {
            size_t cb = (size_t)(q * 4 + j) * H;
            rr[j] = tex[cb + iy0] * (1.f - wy) + tex[cb + iy1] * wy;
        }
        r = make_float4(rr[0], rr[1], rr[2], rr[3]);
    }
    return r;
}

// ---------------------------------------------------------------------------
// Main kernel: one thread per (sample, channel-quad). 4M threads.
// ---------------------------------------------------------------------------
template <bool TRANS>
__global__ __launch_bounds__(256) void td_main(
    const float* __restrict__ coords_plane,
    const float* __restrict__ coords_line,
    const float* __restrict__ pxy, const float* __restrict__ pyz,
    const float* __restrict__ pxz,
    const float* __restrict__ lx, const float* __restrict__ ly,
    const float* __restrict__ lz,
    float* __restrict__ out)
{
    int gid = blockIdx.x * blockDim.x + threadIdx.x;
    int i = gid >> 2;
    int q = gid & 3;
    if (i >= NPTS) return;

    const float2* cp = (const float2*)coords_plane;
    const float2* cl = (const float2*)coords_line;
    float2 g_xy = cp[i];                 // for plane_xy
    float2 g_yz = cp[NPTS + i];          // for plane_yz
    float2 g_xz = cp[2 * NPTS + i];      // for plane_xz
    float  gl_x = cl[i].y;               // line uses grid[:,1] (W==1)
    float  gl_y = cl[NPTS + i].y;
    float  gl_z = cl[2 * NPTS + i].y;

    // plane_xy: (C, Y, X) -> W=X, H=Y
    float4 f_xy = bilinear4<TRANS>(pxy, g_xy.x, g_xy.y, XDIM, YDIM, q);
    // plane_yz: (C, Z, Y) -> W=Y, H=Z
    float4 f_yz = bilinear4<TRANS>(pyz, g_yz.x, g_yz.y, YDIM, ZDIM, q);
    // plane_xz: (C, Z, X) -> W=X, H=Z
    float4 f_xz = bilinear4<TRANS>(pxz, g_xz.x, g_xz.y, XDIM, ZDIM, q);

    float4 f_x = linear4<TRANS>(lx, gl_x, XDIM, q);
    float4 f_y = linear4<TRANS>(ly, gl_y, YDIM, q);
    float4 f_z = linear4<TRANS>(lz, gl_z, ZDIM, q);

    float4* out4 = (float4*)out;
    size_t base = (size_t)i * 4 + q;
    out4[base]                        = mul4(f_yz, f_x);  // out_x
    out4[(size_t)NPTS * 4 + base]     = mul4(f_xz, f_y);  // out_y
    out4[(size_t)NPTS * 8 + base]     = mul4(f_xy, f_z);  // out_z
}

// ---------------------------------------------------------------------------
extern "C" void kernel_launch(void* const* d_in, const int* in_sizes, int n_in,
                              void* d_out, int out_size, void* d_ws, size_t ws_size,
                              hipStream_t stream)
{
    const float* coords_plane = (const float*)d_in[0];
    const float* coords_line  = (const float*)d_in[1];
    const float* pxy = (const float*)d_in[2];
    const float* pyz = (const float*)d_in[3];
    const float* pxz = (const float*)d_in[4];
    const float* lx  = (const float*)d_in[5];
    const float* ly  = (const float*)d_in[6];
    const float* lz  = (const float*)d_in[7];
    float* out = (float*)d_out;

    const size_t planeF = (size_t)XDIM * YDIM * CCH;   // 1,440,000 floats each
    const size_t lineF  = (size_t)XDIM * CCH;          // 4,800 floats each
    const size_t needBytes = (3 * planeF + 3 * lineF) * sizeof(float);

    const int total = NPTS * 4;
    const int blocks = (total + 255) / 256;

    if (ws_size >= needBytes) {
        float* w   = (float*)d_ws;
        float* txy = w;
        float* tyz = w + planeF;
        float* txz = w + 2 * planeF;
        float* tlx = w + 3 * planeF;
        float* tly = tlx + lineF;
        float* tlz = tly + lineF;

        dim3 gp((XDIM * YDIM + 63) / 64, 3);
        transpose3<<<gp, 256, 0, stream>>>(pxy, pyz, pxz, txy, tyz, txz, XDIM * YDIM);
        dim3 gl((XDIM + 63) / 64, 3);
        transpose3<<<gl, 256, 0, stream>>>(lx, ly, lz, tlx, tly, tlz, XDIM);

        td_main<true><<<blocks, 256, 0, stream>>>(coords_plane, coords_line,
                                                  txy, tyz, txz, tlx, tly, tlz, out);
    } else {
        td_main<false><<<blocks, 256, 0, stream>>>(coords_plane, coords_line,
                                                   pxy, pyz, pxz, lx, ly, lz, out);
    }
}

// Round 2
// 125.145 us; speedup vs baseline: 1.5377x; 1.5377x over previous
//
#include <hip/hip_runtime.h>

#define DIMSZ 300
#define CCH   16
#define NPTS  1048576

typedef _Float16 half4 __attribute__((ext_vector_type(4)));

__device__ __forceinline__ float4 h2f(half4 h) {
    return make_float4((float)h[0], (float)h[1], (float)h[2], (float)h[3]);
}
__device__ __forceinline__ float4 mul4(float4 a, float4 b) {
    return make_float4(a.x * b.x, a.y * b.y, a.z * b.z, a.w * b.w);
}

// ---------------------------------------------------------------------------
// Planes: (C, HW) f32  ->  (HW, C) fp16.  blockIdx.y selects which plane.
// ---------------------------------------------------------------------------
__global__ __launch_bounds__(256) void transpose_planes(
    const float* __restrict__ a, const float* __restrict__ b, const float* __restrict__ c,
    _Float16* __restrict__ ta, _Float16* __restrict__ tb, _Float16* __restrict__ tc)
{
    const int HW = DIMSZ * DIMSZ;
    const float* in  = (blockIdx.y == 0) ? a  : (blockIdx.y == 1) ? b  : c;
    _Float16*    out = (blockIdx.y == 0) ? ta : (blockIdx.y == 1) ? tb : tc;

    __shared__ float tile[64][CCH + 1];
    int pix0 = blockIdx.x * 64;
    int t = threadIdx.x;

    // read: 64 pixels x 16 channels, coalesced along pixels
    int p  = t & 63;
    int cg = t >> 6;   // 0..3
#pragma unroll
    for (int k = 0; k < 4; ++k) {
        int ch  = cg * 4 + k;
        int pix = pix0 + p;
        tile[p][ch] = (pix < HW) ? in[(size_t)ch * HW + pix] : 0.f;
    }
    __syncthreads();

    // write: half4 per (pixel, quad), coalesced
    int q  = t & 3;
    int pr = t >> 2;   // 0..63
    int pix = pix0 + pr;
    if (pix < HW) {
        half4 h;
        h[0] = (_Float16)tile[pr][q * 4 + 0];
        h[1] = (_Float16)tile[pr][q * 4 + 1];
        h[2] = (_Float16)tile[pr][q * 4 + 2];
        h[3] = (_Float16)tile[pr][q * 4 + 3];
        ((half4*)out)[(size_t)pix * 4 + q] = h;
    }
}

// ---------------------------------------------------------------------------
// Lines: (C, H) f32 -> (H, C) f32.  Tiny. blockIdx.y selects line.
// ---------------------------------------------------------------------------
__global__ __launch_bounds__(256) void transpose_lines(
    const float* __restrict__ a, const float* __restrict__ b, const float* __restrict__ c,
    float* __restrict__ ta, float* __restrict__ tb, float* __restrict__ tc)
{
    const float* in  = (blockIdx.y == 0) ? a  : (blockIdx.y == 1) ? b  : c;
    float*       out = (blockIdx.y == 0) ? ta : (blockIdx.y == 1) ? tb : tc;
    for (int idx = threadIdx.x; idx < DIMSZ * CCH; idx += 256) {
        int p  = idx >> 4;
        int ch = idx & 15;
        out[idx] = in[ch * DIMSZ + p];
    }
}

// ---------------------------------------------------------------------------
// Per-plane main kernel. K = output slot (0: yz*x, 1: xz*y, 2: xy*z).
// Plane tex is fp16 (HW, C); line tex is f32 (H, C). One thread per
// (sample, channel-quad).
// ---------------------------------------------------------------------------
template <int K>
__global__ __launch_bounds__(256) void td_plane(
    const float* __restrict__ coords_plane,
    const float* __restrict__ coords_line,
    const _Float16* __restrict__ ptex,
    const float* __restrict__ ltex,
    float* __restrict__ out)
{
    int gid = blockIdx.x * 256 + threadIdx.x;
    int i = gid >> 2;
    int q = gid & 3;
    if (i >= NPTS) return;

    // out_x uses plane coords slice 1 (yz), out_y slice 2 (xz), out_z slice 0 (xy)
    constexpr int PC = (K == 0) ? 1 : (K == 1) ? 2 : 0;

    const float2* cp = (const float2*)coords_plane;
    const float2* cl = (const float2*)coords_line;
    float2 g  = cp[(size_t)PC * NPTS + i];
    float  gl = cl[(size_t)K * NPTS + i].y;   // lines use grid[:,1] (W==1)

    // ---- plane bilinear (W = H = 300) ----
    float ix = (g.x + 1.f) * 0.5f * (float)(DIMSZ - 1);
    float iy = (g.y + 1.f) * 0.5f * (float)(DIMSZ - 1);
    float ix0f = floorf(ix), iy0f = floorf(iy);
    float wx = ix - ix0f, wy = iy - iy0f;
    int ix0 = min(max((int)ix0f, 0), DIMSZ - 1);
    int ix1 = min(ix0 + 1, DIMSZ - 1);
    int iy0 = min(max((int)iy0f, 0), DIMSZ - 1);
    int iy1 = min(iy0 + 1, DIMSZ - 1);

    const half4* t4 = (const half4*)ptex;
    size_t r0 = (size_t)iy0 * DIMSZ;
    size_t r1 = (size_t)iy1 * DIMSZ;
    float4 v00 = h2f(t4[(r0 + ix0) * 4 + q]);
    float4 v01 = h2f(t4[(r0 + ix1) * 4 + q]);
    float4 v10 = h2f(t4[(r1 + ix0) * 4 + q]);
    float4 v11 = h2f(t4[(r1 + ix1) * 4 + q]);

    float w00 = (1.f - wx) * (1.f - wy);
    float w01 = wx * (1.f - wy);
    float w10 = (1.f - wx) * wy;
    float w11 = wx * wy;

    float4 f;
    f.x = v00.x * w00 + v01.x * w01 + v10.x * w10 + v11.x * w11;
    f.y = v00.y * w00 + v01.y * w01 + v10.y * w10 + v11.y * w11;
    f.z = v00.z * w00 + v01.z * w01 + v10.z * w10 + v11.z * w11;
    f.w = v00.w * w00 + v01.w * w01 + v10.w * w10 + v11.w * w11;

    // ---- line linear (H = 300) ----
    float lyv = (gl + 1.f) * 0.5f * (float)(DIMSZ - 1);
    float ly0f = floorf(lyv);
    float wl = lyv - ly0f;
    int l0 = min(max((int)ly0f, 0), DIMSZ - 1);
    int l1 = min(l0 + 1, DIMSZ - 1);

    const float4* l4 = (const float4*)ltex;
    float4 u0 = l4[(size_t)l0 * 4 + q];
    float4 u1 = l4[(size_t)l1 * 4 + q];
    float4 fl;
    fl.x = u0.x * (1.f - wl) + u1.x * wl;
    fl.y = u0.y * (1.f - wl) + u1.y * wl;
    fl.z = u0.z * (1.f - wl) + u1.z * wl;
    fl.w = u0.w * (1.f - wl) + u1.w * wl;

    float4* out4 = (float4*)out;
    out4[(size_t)K * NPTS * 4 + (size_t)i * 4 + q] = mul4(f, fl);
}

// ---------------------------------------------------------------------------
// Fallback (no usable ws): direct f32 gather from original (C,H,W) layout.
// ---------------------------------------------------------------------------
__global__ __launch_bounds__(256) void td_fallback(
    const float* __restrict__ coords_plane,
    const float* __restrict__ coords_line,
    const float* __restrict__ pxy, const float* __restrict__ pyz,
    const float* __restrict__ pxz,
    const float* __restrict__ lx, const float* __restrict__ ly,
    const float* __restrict__ lz,
    float* __restrict__ out)
{
    int gid = blockIdx.x * 256 + threadIdx.x;
    int i = gid >> 2;
    int q = gid & 3;
    if (i >= NPTS) return;

    const float2* cp = (const float2*)coords_plane;
    const float2* cl = (const float2*)coords_line;

    float4* out4 = (float4*)out;
    const float* planes[3] = {pyz, pxz, pxy};
    const float* lines[3]  = {lx, ly, lz};
    const int    pcs[3]    = {1, 2, 0};

#pragma unroll
    for (int k = 0; k < 3; ++k) {
        float2 g  = cp[(size_t)pcs[k] * NPTS + i];
        float  gl = cl[(size_t)k * NPTS + i].y;

        float ix = (g.x + 1.f) * 0.5f * (float)(DIMSZ - 1);
        float iy = (g.y + 1.f) * 0.5f * (float)(DIMSZ - 1);
        float ix0f = floorf(ix), iy0f = floorf(iy);
        float wx = ix - ix0f, wy = iy - iy0f;
        int ix0 = min(max((int)ix0f, 0), DIMSZ - 1);
        int ix1 = min(ix0 + 1, DIMSZ - 1);
        int iy0 = min(max((int)iy0f, 0), DIMSZ - 1);
        int iy1 = min(iy0 + 1, DIMSZ - 1);
        float w00 = (1.f - wx) * (1.f - wy), w01 = wx * (1.f - wy);
        float w10 = (1.f - wx) * wy,         w11 = wx * wy;

        float lyv = (gl + 1.f) * 0.5f * (float)(DIMSZ - 1);
        float ly0f = floorf(lyv);
        float wl = lyv - ly0f;
        int l0 = min(max((int)ly0f, 0), DIMSZ - 1);
        int l1 = min(l0 + 1, DIMSZ - 1);

        const float* P = planes[k];
        const float* L = lines[k];
        size_t hw = (size_t)DIMSZ * DIMSZ;
        int b00 = iy0 * DIMSZ + ix0, b01 = iy0 * DIMSZ + ix1;
        int b10 = iy1 * DIMSZ + ix0, b11 = iy1 * DIMSZ + ix1;
        float4 r;
        float rr[4];
#pragma unroll
        for (int j = 0; j < 4; ++j) {
            size_t cb = (size_t)(q * 4 + j) * hw;
            float fp = P[cb + b00] * w00 + P[cb + b01] * w01 +
                       P[cb + b10] * w10 + P[cb + b11] * w11;
            size_t lb = (size_t)(q * 4 + j) * DIMSZ;
            float flv = L[lb + l0] * (1.f - wl) + L[lb + l1] * wl;
            rr[j] = fp * flv;
        }
        r = make_float4(rr[0], rr[1], rr[2], rr[3]);
        out4[(size_t)k * NPTS * 4 + (size_t)i * 4 + q] = r;
    }
}

// ---------------------------------------------------------------------------
extern "C" void kernel_launch(void* const* d_in, const int* in_sizes, int n_in,
                              void* d_out, int out_size, void* d_ws, size_t ws_size,
                              hipStream_t stream)
{
    const float* coords_plane = (const float*)d_in[0];
    const float* coords_line  = (const float*)d_in[1];
    const float* pxy = (const float*)d_in[2];
    const float* pyz = (const float*)d_in[3];
    const float* pxz = (const float*)d_in[4];
    const float* lx  = (const float*)d_in[5];
    const float* ly  = (const float*)d_in[6];
    const float* lz  = (const float*)d_in[7];
    float* out = (float*)d_out;

    const size_t planeH = (size_t)DIMSZ * DIMSZ * CCH;         // halves per plane
    const size_t lineF  = (size_t)DIMSZ * CCH;                 // floats per line
    const size_t needBytes = 3 * planeH * sizeof(_Float16) + 3 * lineF * sizeof(float);

    const int blocks = (NPTS * 4 + 255) / 256;

    if (ws_size >= needBytes) {
        char* w = (char*)d_ws;
        _Float16* txy = (_Float16*)w;
        _Float16* tyz = txy + planeH;
        _Float16* txz = tyz + planeH;
        float* tlx = (float*)(w + 3 * planeH * sizeof(_Float16));
        float* tly = tlx + lineF;
        float* tlz = tly + lineF;

        dim3 gp((DIMSZ * DIMSZ + 63) / 64, 3);
        transpose_planes<<<gp, 256, 0, stream>>>(pxy, pyz, pxz, txy, tyz, txz);
        dim3 gl(1, 3);
        transpose_lines<<<gl, 256, 0, stream>>>(lx, ly, lz, tlx, tly, tlz);

        // sequential per-plane kernels: each has a single 2.88 MB fp16 plane
        // as its gather working set -> fits in one XCD's 4 MB L2.
        td_plane<0><<<blocks, 256, 0, stream>>>(coords_plane, coords_line, tyz, tlx, out);
        td_plane<1><<<blocks, 256, 0, stream>>>(coords_plane, coords_line, txz, tly, out);
        td_plane<2><<<blocks, 256, 0, stream>>>(coords_plane, coords_line, txy, tlz, out);
    } else {
        td_fallback<<<blocks, 256, 0, stream>>>(coords_plane, coords_line,
                                                pxy, pyz, pxz, lx, ly, lz, out);
    }
}